// Round 11
// baseline (89.706 us; speedup 1.0000x reference)
//
#include <hip/hip_runtime.h>
#include <math.h>

// ---------------------------------------------------------------------------
// RopeAttentionModel reduced form:
//   x[s,:] = c_s * ones(HID)  =>  q/k/v rank-1: c_s * colsum(W)
//   scores[s,hg,k] = c_s*c_k * D[hg, s-k] / sqrt(128)
//   D[hg,d] = sum_j P[hg,j]*cos(d*f_j) - Q[hg,j]*sin(d*f_j)   (f64)
//   alpha[s,hg] = softmax-weighted mean of c_k  (scalar per (s,head))
//   out[s,:] = sum_hg alpha[s,hg] * M[hg,:],  M[hg,:] = Sv[h] . Wo-block
// 4 dispatches: k_part -> k_dtab (redundant col-reduce + D) ->
// k_fuse (M slabs || alpha) -> k_out.  Plain loads; no buffer is written
// after a later kernel reads the same region (Mp aliases dead Tc/Ts only).
// ---------------------------------------------------------------------------

#define HID 4096
#define NQH 32
#define NKVH 8
#define HD 128
#define CHQ 128                   // partial depth (rows folded per column)
#define TS 64                     // s-rows per alpha block (one per lane)
#define RSQRT_HD 0.08838834764831845f
#define LOG2E    1.4426950408889634f

// sequential grid-stride column sum: thread u reads b[u + k*nth4], k=0..31.
// column (u mod cols4) invariant since nth4 % cols4 == 0.
// Partial written flat at P[u] == P[depth][col], depth = u / cols4 in [0,128).
__device__ __forceinline__ void colsum_seq(const float* __restrict__ W,
                                           float* __restrict__ P,
                                           int nth4, int u) {
    const float4* b = reinterpret_cast<const float4*>(W);
    float ax = 0.f, ay = 0.f, az = 0.f, aw = 0.f;
#pragma unroll
    for (int k = 0; k < 32; k += 8) {
        float4 tt[8];
#pragma unroll
        for (int i = 0; i < 8; ++i) tt[i] = b[(size_t)(k + i) * nth4 + u];
#pragma unroll
        for (int i = 0; i < 8; i += 4) {
            ax += (tt[i].x + tt[i+1].x) + (tt[i+2].x + tt[i+3].x);
            ay += (tt[i].y + tt[i+1].y) + (tt[i+2].y + tt[i+3].y);
            az += (tt[i].z + tt[i+1].z) + (tt[i+2].z + tt[i+3].z);
            aw += (tt[i].w + tt[i+1].w) + (tt[i+2].w + tt[i+3].w);
        }
    }
    reinterpret_cast<float4*>(P)[u] = make_float4(ax, ay, az, aw);
}

// ---- fused: trig table + cp + Wq/Wk/Wv sequential colsums ----
__global__ __launch_bounds__(256) void k_part(
        const int* __restrict__ ids,
        const float* __restrict__ Wq, const float* __restrict__ Wk,
        const float* __restrict__ Wv,
        float* __restrict__ Pq, float* __restrict__ Pk, float* __restrict__ Pv,
        float* __restrict__ cp, double* __restrict__ Tc,
        double* __restrict__ Ts, int S) {
    int t = blockIdx.x;
    int tid = threadIdx.x;
    int nxb = S >> 8;
    int trigT = 64 * nxb;                     // 512
    if (t < trigT) {
        int j = t / nxb, xb = t - j * nxb;
        int dlt = xb * 256 + tid;
        double f = (double)(float)(1.0 / pow(10000.0, (double)j / 64.0));
        double sv, cv;
        sincos((double)dlt * f, &sv, &cv);
        Tc[(size_t)j * S + dlt] = cv;
        Ts[(size_t)j * S + dlt] = sv;
        if (j == 0) cp[dlt] = (float)ids[dlt];
    } else if (t < trigT + 512) {
        colsum_seq(Wq, Pq, 512 * 256, (t - trigT) * 256 + tid);
    } else if (t < trigT + 640) {
        colsum_seq(Wk, Pk, 128 * 256, (t - trigT - 512) * 256 + tid);
    } else {
        colsum_seq(Wv, Pv, 128 * 256, (t - trigT - 640) * 256 + tid);
    }
}

// ---- D table: each block redundantly reduces its Pq/Pk columns (L2-hot),
//      then computes 256 dlt points in f64 from the trig table ----
__global__ __launch_bounds__(256) void k_dtab(
        const float* __restrict__ Pq, const float* __restrict__ Pk,
        const double* __restrict__ Tc, const double* __restrict__ Ts,
        float* __restrict__ D, int S) {
    __shared__ float sq[128], sk[128];
    __shared__ double p[64], q[64];
    int nxb = S >> 8;
    int hg = blockIdx.x / nxb, xb = blockIdx.x - hg * nxb, h = hg >> 2;
    int tid = threadIdx.x;
    if (tid < 128) {
        const float* base = Pq + hg * HD + tid;     // stride 4096 floats
        float a = 0.f;
#pragma unroll 16
        for (int dep = 0; dep < CHQ; ++dep) a += base[(size_t)dep * 4096];
        sq[tid] = a;
    } else {
        int d = tid - 128;
        const float* base = Pk + h * HD + d;        // stride 1024 floats
        float a = 0.f;
#pragma unroll 16
        for (int dep = 0; dep < CHQ; ++dep) a += base[(size_t)dep * 1024];
        sk[d] = a;
    }
    __syncthreads();
    if (tid < 64) {
        double a1 = sq[tid], a2 = sq[tid + 64];
        double b1 = sk[tid], b2 = sk[tid + 64];
        p[tid] = a1 * b1 + a2 * b2;
        q[tid] = a2 * b1 - a1 * b2;
    }
    __syncthreads();
    int dlt = xb * 256 + tid;
    const double* tc = Tc + dlt;
    const double* ts = Ts + dlt;
    double acc = 0.0;
#pragma unroll 8
    for (int j = 0; j < 64; ++j)
        acc += p[j] * tc[(size_t)j * S] - q[j] * ts[(size_t)j * S];
    D[(size_t)hg * S + dlt] = (float)acc;
}

// ---- fused: Mp slabs (Sv.Wo, local Sv reduce) || alpha ----
__global__ __launch_bounds__(256) void k_fuse(
        const int* __restrict__ ids, const float* __restrict__ cp,
        const float* __restrict__ D, const float* __restrict__ Pv,
        const float* __restrict__ Wo, float* __restrict__ Mp,
        float* __restrict__ A, int S) {
    int t = blockIdx.x;
    int tid = threadIdx.x;
    if (t < 512) {
        // Mp[sl][hg][:] = Sv[h, sl*32:+32] . Wo[hg*128+sl*32 : +32, :]
        __shared__ float part[8][32];
        __shared__ float svs[32];
        int sl = t & 3, x = (t >> 2) & 3, hg = t >> 4, h = hg >> 2;
        {   // redundant Sv reduce for this slab (16 KB from L2)
            int j = tid & 31, g = tid >> 5;
            const float* base = Pv + (size_t)(g * 16) * 1024 + h * HD + sl * 32 + j;
            float a = 0.f;
#pragma unroll
            for (int dep = 0; dep < 16; ++dep) a += base[(size_t)dep * 1024];
            part[g][j] = a;
        }
        __syncthreads();
        if (tid < 32) {
            float a = 0.f;
#pragma unroll
            for (int g = 0; g < 8; ++g) a += part[g][tid];
            svs[tid] = a;
        }
        __syncthreads();
        int dbase = hg * HD + sl * 32;
        int i4 = x * 256 + tid;
        const float4* b = reinterpret_cast<const float4*>(Wo);
        float ax = 0.f, ay = 0.f, az = 0.f, aw = 0.f;
#pragma unroll
        for (int bb = 0; bb < 4; ++bb) {
            size_t pbase = (size_t)(dbase + bb * 8) * (HID / 4) + i4;
            float4 tt[8];
#pragma unroll
            for (int i = 0; i < 8; ++i) tt[i] = b[pbase + (size_t)i * (HID / 4)];
#pragma unroll
            for (int i = 0; i < 8; ++i) {
                float ss = svs[bb * 8 + i];
                ax += ss * tt[i].x; ay += ss * tt[i].y;
                az += ss * tt[i].z; aw += ss * tt[i].w;
            }
        }
        reinterpret_cast<float4*>(Mp)[((size_t)sl * NQH + hg) * (HID / 4) + i4] =
            make_float4(ax, ay, az, aw);
        return;
    }
    // ---- alpha: lane-per-row; block = (hg, 64-row tile); 4 waves split k ----
    int u = t - 512;
    int tile = u >> 5;
    int hg = u & 31;
    int s0 = S - TS - tile * TS;
    int w = tid >> 6, lane = tid & 63;
    int sl = s0 + lane;
    float csl = (float)ids[sl] * (RSQRT_HD * LOG2E);
    const float* Drow = D + (size_t)hg * S + sl;

    int n = s0 + TS;
    int q4 = ((n + 15) >> 4) << 2;
    int k = w * q4;
    int k1 = (k + q4 < n) ? k + q4 : n;
    int lim = (k1 < s0 + 1) ? k1 : s0 + 1;

    float tm = -1e30f;
    float mz = csl * tm;
    float se = 0.f, sp = 0.f;

    for (; k + 8 <= lim; k += 8) {
        float4 cv0 = *reinterpret_cast<const float4*>(cp + k);
        float4 cv1 = *reinterpret_cast<const float4*>(cp + k + 4);
        float d0 = Drow[-k],     d1 = Drow[-(k+1)], d2 = Drow[-(k+2)], d3 = Drow[-(k+3)];
        float d4 = Drow[-(k+4)], d5 = Drow[-(k+5)], d6 = Drow[-(k+6)], d7 = Drow[-(k+7)];
        float t0 = cv0.x * d0, t1 = cv0.y * d1, t2 = cv0.z * d2, t3 = cv0.w * d3;
        float t4 = cv1.x * d4, t5 = cv1.y * d5, t6 = cv1.z * d6, t7 = cv1.w * d7;
        float m8 = fmaxf(fmaxf(fmaxf(t0, t1), fmaxf(t2, t3)),
                         fmaxf(fmaxf(t4, t5), fmaxf(t6, t7)));
        if (!__all(m8 <= tm)) {
            float ntm = fmaxf(tm, m8);
            float nmz = csl * ntm;
            float r = __builtin_amdgcn_exp2f(fminf(mz - nmz, 0.f));
            se *= r; sp *= r; tm = ntm; mz = nmz;
        }
        float e0 = __builtin_amdgcn_exp2f(fmaf(csl, t0, -mz));
        float e1 = __builtin_amdgcn_exp2f(fmaf(csl, t1, -mz));
        float e2 = __builtin_amdgcn_exp2f(fmaf(csl, t2, -mz));
        float e3 = __builtin_amdgcn_exp2f(fmaf(csl, t3, -mz));
        float e4 = __builtin_amdgcn_exp2f(fmaf(csl, t4, -mz));
        float e5 = __builtin_amdgcn_exp2f(fmaf(csl, t5, -mz));
        float e6 = __builtin_amdgcn_exp2f(fmaf(csl, t6, -mz));
        float e7 = __builtin_amdgcn_exp2f(fmaf(csl, t7, -mz));
        se += ((e0 + e1) + (e2 + e3)) + ((e4 + e5) + (e6 + e7));
        sp = fmaf(e0, cv0.x, sp); sp = fmaf(e1, cv0.y, sp);
        sp = fmaf(e2, cv0.z, sp); sp = fmaf(e3, cv0.w, sp);
        sp = fmaf(e4, cv1.x, sp); sp = fmaf(e5, cv1.y, sp);
        sp = fmaf(e6, cv1.z, sp); sp = fmaf(e7, cv1.w, sp);
    }
    for (; k + 4 <= lim; k += 4) {
        float4 cv = *reinterpret_cast<const float4*>(cp + k);
        float d0 = Drow[-k], d1 = Drow[-(k+1)], d2 = Drow[-(k+2)], d3 = Drow[-(k+3)];
        float t0 = cv.x * d0, t1 = cv.y * d1, t2 = cv.z * d2, t3 = cv.w * d3;
        float m4 = fmaxf(fmaxf(t0, t1), fmaxf(t2, t3));
        if (!__all(m4 <= tm)) {
            float ntm = fmaxf(tm, m4);
            float nmz = csl * ntm;
            float r = __builtin_amdgcn_exp2f(fminf(mz - nmz, 0.f));
            se *= r; sp *= r; tm = ntm; mz = nmz;
        }
        float e0 = __builtin_amdgcn_exp2f(fmaf(csl, t0, -mz));
        float e1 = __builtin_amdgcn_exp2f(fmaf(csl, t1, -mz));
        float e2 = __builtin_amdgcn_exp2f(fmaf(csl, t2, -mz));
        float e3 = __builtin_amdgcn_exp2f(fmaf(csl, t3, -mz));
        se += (e0 + e1) + (e2 + e3);
        sp = fmaf(e0, cv.x, sp); sp = fmaf(e1, cv.y, sp);
        sp = fmaf(e2, cv.z, sp); sp = fmaf(e3, cv.w, sp);
    }
    for (; k < k1; k += 4) {
        float4 cv = *reinterpret_cast<const float4*>(cp + k);
        float d0 = Drow[-k], d1 = Drow[-(k+1)], d2 = Drow[-(k+2)], d3 = Drow[-(k+3)];
        bool v0 = (k + 0 <= sl) && (k + 0 < k1);
        bool v1 = (k + 1 <= sl) && (k + 1 < k1);
        bool v2 = (k + 2 <= sl) && (k + 2 < k1);
        bool v3 = (k + 3 <= sl) && (k + 3 < k1);
        float t0 = v0 ? cv.x * d0 : -1e30f;
        float t1 = v1 ? cv.y * d1 : -1e30f;
        float t2 = v2 ? cv.z * d2 : -1e30f;
        float t3 = v3 ? cv.w * d3 : -1e30f;
        float m4 = fmaxf(fmaxf(t0, t1), fmaxf(t2, t3));
        if (!__all(m4 <= tm)) {
            float ntm = fmaxf(tm, m4);
            float nmz = csl * ntm;
            float r = __builtin_amdgcn_exp2f(fminf(mz - nmz, 0.f));
            se *= r; sp *= r; tm = ntm; mz = nmz;
        }
        float e0 = __builtin_amdgcn_exp2f(fmaf(csl, t0, -mz)); e0 = v0 ? e0 : 0.f;
        float e1 = __builtin_amdgcn_exp2f(fmaf(csl, t1, -mz)); e1 = v1 ? e1 : 0.f;
        float e2 = __builtin_amdgcn_exp2f(fmaf(csl, t2, -mz)); e2 = v2 ? e2 : 0.f;
        float e3 = __builtin_amdgcn_exp2f(fmaf(csl, t3, -mz)); e3 = v3 ? e3 : 0.f;
        se += (e0 + e1) + (e2 + e3);
        sp = fmaf(e0, cv.x, sp); sp = fmaf(e1, cv.y, sp);
        sp = fmaf(e2, cv.z, sp); sp = fmaf(e3, cv.w, sp);
    }

    __shared__ float lm[4][TS], ls[4][TS], lp[4][TS];
    lm[w][lane] = mz; ls[w][lane] = se; lp[w][lane] = sp;
    __syncthreads();
    if (tid < TS) {
        float m0 = lm[0][tid], m1 = lm[1][tid], m2 = lm[2][tid], m3 = lm[3][tid];
        float mm = fmaxf(fmaxf(m0, m1), fmaxf(m2, m3));
        float r0 = __builtin_amdgcn_exp2f(fminf(m0 - mm, 0.f));
        float r1 = __builtin_amdgcn_exp2f(fminf(m1 - mm, 0.f));
        float r2 = __builtin_amdgcn_exp2f(fminf(m2 - mm, 0.f));
        float r3 = __builtin_amdgcn_exp2f(fminf(m3 - mm, 0.f));
        float seT = ls[0][tid] * r0 + ls[1][tid] * r1 + ls[2][tid] * r2 + ls[3][tid] * r3;
        float spT = lp[0][tid] * r0 + lp[1][tid] * r1 + lp[2][tid] * r2 + lp[3][tid] * r3;
        A[(size_t)hg * S + s0 + tid] = spT / seT;
    }
}

// ---- final: out[s,:] = sum_hg A[hg][s] * (sum of 4 Mp slabs)[hg][:] ----
__global__ void k_out(const float* __restrict__ A, const float* __restrict__ Mp,
                      float* __restrict__ out, int S) {
    __shared__ float a[512];                       // [16 rows][32 hg]
    int tid = threadIdx.x;
    int s0 = blockIdx.y * 16;
    for (int v = tid; v < 512; v += 256) {
        int hg = v >> 4, r = v & 15;
        a[r * NQH + hg] = A[(size_t)hg * S + s0 + r];
    }
    __syncthreads();
    int i = blockIdx.x * 256 + tid;
    const int Q = NQH * HID;
    float acc[16];
#pragma unroll
    for (int rr = 0; rr < 16; ++rr) acc[rr] = 0.f;
    for (int hg = 0; hg < NQH; ++hg) {
        size_t base = (size_t)hg * HID + i;
        float mv = (Mp[base] + Mp[base + Q]) + (Mp[base + 2 * Q] + Mp[base + 3 * Q]);
#pragma unroll
        for (int rr = 0; rr < 16; ++rr) acc[rr] += a[rr * NQH + hg] * mv;
    }
#pragma unroll
    for (int rr = 0; rr < 16; ++rr)
        out[(size_t)(s0 + rr) * HID + i] = acc[rr];
}

extern "C" void kernel_launch(void* const* d_in, const int* in_sizes, int n_in,
                              void* d_out, int out_size, void* d_ws, size_t ws_size,
                              hipStream_t stream) {
    const int*   ids = (const int*)d_in[0];
    const float* Wq  = (const float*)d_in[2];
    const float* Wk  = (const float*)d_in[3];
    const float* Wv  = (const float*)d_in[4];
    const float* Wo  = (const float*)d_in[5];
    float* out = (float*)d_out;
    const int S = in_sizes[0];                      // B=1, S=2048
    const int nxb = S >> 8;

    // ws layout (floats unless noted):
    //  [Pq 128*4096][Pk 128*1024][Pv 128*1024][D 32*S][cp S][A 32*S]
    //  [Tc 64*S f64 | Ts 64*S f64]   <- Mp[4][32][4096] ALIASES Tc/Ts
    //  (Tc/Ts dead after k_dtab; k_fuse then writes Mp there; k_out reads it.
    //   No region is written after a later kernel reads its previous contents.)
    float* ws = (float*)d_ws;
    float* Pq = ws;
    float* Pk = Pq + (size_t)CHQ * NQH * HD;
    float* Pv = Pk + (size_t)CHQ * NKVH * HD;
    float* D  = Pv + (size_t)CHQ * NKVH * HD;
    float* cp = D + (size_t)NQH * S;
    float* A  = cp + S;
    double* Tc = (double*)(A + (size_t)NQH * S);
    double* Ts = Tc + (size_t)64 * S;
    float* Mp = (float*)Tc;                         // 4*32*4096 floats == Tc+Ts

    k_part<<<64 * nxb + 512 + 128 + 128, 256, 0, stream>>>(
        ids, Wq, Wk, Wv, Pq, Pk, Pv, cp, Tc, Ts, S);
    k_dtab<<<NQH * nxb, 256, 0, stream>>>(Pq, Pk, Tc, Ts, D, S);
    k_fuse<<<512 + (S / TS) * NQH, 256, 0, stream>>>(ids, cp, D, Pv, Wo, Mp, A, S);
    k_out<<<dim3(HID / 256, S / 16), 256, 0, stream>>>(A, Mp, out, S);
}